// Round 1
// baseline (165.913 us; speedup 1.0000x reference)
//
#include <hip/hip_runtime.h>

#define NB 16
#define NTQ 256
#define NTK 256
#define ND 256
#define NF 36
#define NH 8
#define NDK 32
#define NSF 6

typedef __attribute__((ext_vector_type(8))) short short8;
typedef __attribute__((ext_vector_type(4))) float f32x4;
#define MFMA16(a,b,c) __builtin_amdgcn_mfma_f32_16x16x32_bf16(a,b,c,0,0,0)

// ---- workspace byte offsets ----
// QXH/QXL/KXH/KXL: bf16 hi/lo of query/key, [b][t][d], 2MB each
#define QXH_OFF 0u
#define QXL_OFF  (2u*1024*1024)
#define KXH_OFF  (4u*1024*1024)
#define KXL_OFF  (6u*1024*1024)
// WqT/WkT hi/lo: [j][dk][d] bf16, 128KB each
#define WQTH_OFF (8u*1024*1024)
#define WQTL_OFF (WQTH_OFF + 131072u)
#define WKTH_OFF (WQTH_OFF + 262144u)
#define WKTL_OFF (WQTH_OFF + 393216u)
// RT: [b][80][256] bf16 (f'=2f: m*v, f'=2f+1: m)
#define RT_OFF   (WQTH_OFF + 524288u)
// HD: fp32 [b][j][t][f]
#define HD_OFF   (RT_OFF + 655360u)
// total ~14.3 MB

__device__ __forceinline__ short f2bf(float x){
    union { float f; unsigned u; } v; v.f = x;
    unsigned r = v.u + 0x7fffu + ((v.u >> 16) & 1u);
    return (short)(r >> 16);
}
__device__ __forceinline__ float bf2f(short s){
    union { float f; unsigned u; } v; v.u = ((unsigned)(unsigned short)s) << 16;
    return v.f;
}
__device__ __forceinline__ float fast_tanh(float x){
    float e = __expf(2.0f*x);
    return 1.0f - 2.0f/(e + 1.0f);
}
__device__ __forceinline__ short8 ld8(const short* p){ return *(const short8*)p; }

// hi/lo bf16 split of 8 consecutive floats (RNE hi, RNE residual lo)
__device__ __forceinline__ void cvt8(const float* __restrict__ p, short8& h8, short8& l8){
    f32x4 a = *(const f32x4*)p;
    f32x4 c = *(const f32x4*)(p + 4);
    #pragma unroll
    for (int i = 0; i < 4; ++i){
        short h0 = f2bf(a[i]); h8[i]   = h0; l8[i]   = f2bf(a[i] - bf2f(h0));
        short h1 = f2bf(c[i]); h8[4+i] = h1; l8[4+i] = f2bf(c[i] - bf2f(h1));
    }
}

// ---------------- kernel 1: streaming pack ----------------
// bid <512: query->bf16 hi/lo; <1024: key; <1536: WqT/WkT transpose+split; else RT pack
__global__ void imta_pack(const float* __restrict__ query, const float* __restrict__ key_ts,
                          const float* __restrict__ Wq, const float* __restrict__ Wk,
                          const float* __restrict__ mask, const float* __restrict__ value,
                          char* __restrict__ wsb){
    const int bid = blockIdx.x, tid = threadIdx.x;
    if (bid < 1024){
        const int half = bid >> 9;                  // 0=query 1=key
        const float* __restrict__ X = half ? key_ts : query;
        short* oh = (short*)(wsb + (half ? KXH_OFF : QXH_OFF));
        short* ol = (short*)(wsb + (half ? KXL_OFF : QXL_OFF));
        const int e = ((bid & 511)*256 + tid)*8;    // 512*256*8 = 1,048,576 elems
        short8 h8, l8;
        cvt8(X + e, h8, l8);
        *(short8*)(oh + e) = h8;
        *(short8*)(ol + e) = l8;
        return;
    }
    if (bid < 1536){
        const int idx = (bid - 1024)*256 + tid;     // 131072 = 2 arrays * 65536
        const int arr = idx >> 16, rem = idx & 65535;
        const int d = rem & 255, jdk = rem >> 8;
        const int jj = jdk >> 5, dk = jdk & 31;
        const float* __restrict__ W = arr ? Wk : Wq;
        float v = W[(jj*ND + d)*NDK + dk];
        short h = f2bf(v);
        short* oh = (short*)(wsb + (arr ? WKTH_OFF : WQTH_OFF));
        short* ol = (short*)(wsb + (arr ? WKTL_OFF : WQTL_OFF));
        oh[rem] = h; ol[rem] = f2bf(v - bf2f(h));
        return;
    }
    // RT pack (verbatim from previous prep y==2 path)
    const int rb = bid - 1536;
    const int x = rb & 15, b = rb >> 4;
    const int k = tid;
    short* rt = (short*)(wsb + RT_OFF) + b*80*256;
    #pragma unroll
    for (int r = 0; r < 5; ++r){
        const int fp = x*5 + r;
        const int f = fp >> 1;
        short o = 0;
        if (f < NF){
            float m = mask[(b*NTK + k)*NF + f];
            o = (fp & 1) ? f2bf(m) : f2bf(m * value[(b*NTK + k)*NF + f]);
        }
        rt[fp*256 + k] = o;
    }
}

// ---------------- kernel 2: fused proj + attention ----------------
// block (qtile | j | b), 256 thr. Phase 0: K-proj (wave w -> keys [64w,64w+64))
// + Q-proj (wave w -> 16 q rows) -> hi/lo LDS. Phase 1: scores (3-pass) in regs,
// exp -> sE (overlays K/Q LDS). Phase 2: E @ RT^T -> shfl div -> heads.
__global__ __launch_bounds__(256, 2)
void imta_attn(char* __restrict__ wsb, const float* __restrict__ value){
    const int t0 = blockIdx.x*64;
    const int j = blockIdx.y, b = blockIdx.z;
    const int tid = threadIdx.x, w = tid >> 6, lane = tid & 63;
    const int col = lane & 15, quad = lane >> 4;

    __shared__ short sBuf[20480];          // 40 KB union
    short* const sKH = sBuf;               // [256][32]
    short* const sKL = sBuf + 8192;
    short* const sQH = sBuf + 16384;       // [64][32]
    short* const sQL = sBuf + 18432;

    const short* KXH = (const short*)(wsb + KXH_OFF) + (size_t)b*NTK*ND;
    const short* KXL = (const short*)(wsb + KXL_OFF) + (size_t)b*NTK*ND;
    const short* QXH = (const short*)(wsb + QXH_OFF) + (size_t)b*NTQ*ND;
    const short* QXL = (const short*)(wsb + QXL_OFF) + (size_t)b*NTQ*ND;
    const short* WKH = (const short*)(wsb + WKTH_OFF) + j*NDK*ND;
    const short* WKL = (const short*)(wsb + WKTL_OFF) + j*NDK*ND;
    const short* WQH = (const short*)(wsb + WQTH_OFF) + j*NDK*ND;
    const short* WQL = (const short*)(wsb + WQTL_OFF) + j*NDK*ND;

    // ---- phase 0a: K projection, wave w -> keys [64w, 64w+64) ----
    {
        f32x4 kacc[4][2];
        #pragma unroll
        for (int mt = 0; mt < 4; ++mt){ kacc[mt][0] = (f32x4)0.f; kacc[mt][1] = (f32x4)0.f; }
        #pragma unroll
        for (int kb = 0; kb < 8; ++kb){
            const int dko = kb*32 + quad*8;
            short8 wbh[2], wbl[2];
            #pragma unroll
            for (int nb = 0; nb < 2; ++nb){
                wbh[nb] = ld8(WKH + (nb*16 + col)*ND + dko);
                wbl[nb] = ld8(WKL + (nb*16 + col)*ND + dko);
            }
            #pragma unroll
            for (int mt = 0; mt < 4; ++mt){
                const int krow = w*64 + mt*16 + col;
                short8 ah = ld8(KXH + krow*ND + dko);
                short8 al = ld8(KXL + krow*ND + dko);
                #pragma unroll
                for (int nb = 0; nb < 2; ++nb){
                    kacc[mt][nb] = MFMA16(al, wbh[nb], kacc[mt][nb]);
                    kacc[mt][nb] = MFMA16(ah, wbl[nb], kacc[mt][nb]);
                    kacc[mt][nb] = MFMA16(ah, wbh[nb], kacc[mt][nb]);
                }
            }
        }
        #pragma unroll
        for (int mt = 0; mt < 4; ++mt)
            #pragma unroll
            for (int nb = 0; nb < 2; ++nb)
                #pragma unroll
                for (int r = 0; r < 4; ++r){
                    const int key = w*64 + mt*16 + quad*4 + r;
                    const int dk  = nb*16 + col;
                    float v = kacc[mt][nb][r];
                    short h = f2bf(v);
                    sKH[key*32 + dk] = h;
                    sKL[key*32 + dk] = f2bf(v - bf2f(h));
                }
    }
    // ---- phase 0b: Q projection, wave w -> q rows [16w, 16w+16) ----
    {
        f32x4 qacc[2]; qacc[0] = (f32x4)0.f; qacc[1] = (f32x4)0.f;
        #pragma unroll
        for (int kb = 0; kb < 8; ++kb){
            const int dko = kb*32 + quad*8;
            short8 ah = ld8(QXH + (t0 + w*16 + col)*ND + dko);
            short8 al = ld8(QXL + (t0 + w*16 + col)*ND + dko);
            #pragma unroll
            for (int nb = 0; nb < 2; ++nb){
                short8 wbh = ld8(WQH + (nb*16 + col)*ND + dko);
                short8 wbl = ld8(WQL + (nb*16 + col)*ND + dko);
                qacc[nb] = MFMA16(al, wbh, qacc[nb]);
                qacc[nb] = MFMA16(ah, wbl, qacc[nb]);
                qacc[nb] = MFMA16(ah, wbh, qacc[nb]);
            }
        }
        #pragma unroll
        for (int nb = 0; nb < 2; ++nb)
            #pragma unroll
            for (int r = 0; r < 4; ++r){
                const int q  = w*16 + quad*4 + r;
                const int dk = nb*16 + col;
                float v = qacc[nb][r];
                short h = f2bf(v);
                sQH[q*32 + dk] = h;
                sQL[q*32 + dk] = f2bf(v - bf2f(h));
            }
    }
    __syncthreads();

    // ---- phase 1: scores, wave w -> keys [64w,64w+64) x all 64 q (in regs) ----
    f32x4 sacc[4][4];
    {
        short8 aqh[4], aql[4];
        #pragma unroll
        for (int m = 0; m < 4; ++m){
            aqh[m] = *(const short8*)&sQH[(m*16 + col)*32 + quad*8];
            aql[m] = *(const short8*)&sQL[(m*16 + col)*32 + quad*8];
        }
        #pragma unroll
        for (int nt = 0; nt < 4; ++nt){
            const int krow = w*64 + nt*16 + col;
            short8 bh = *(const short8*)&sKH[krow*32 + quad*8];
            short8 bl = *(const short8*)&sKL[krow*32 + quad*8];
            #pragma unroll
            for (int m = 0; m < 4; ++m){
                f32x4 c = (f32x4)0.f;
                c = MFMA16(aql[m], bh, c);
                c = MFMA16(aqh[m], bl, c);
                c = MFMA16(aqh[m], bh, c);
                sacc[nt][m] = c;
            }
        }
    }
    __syncthreads();                       // all K/Q LDS reads done before overlay

    short* const sE = sBuf;                // [64][264] overlays K/Q
    #pragma unroll
    for (int nt = 0; nt < 4; ++nt)
        #pragma unroll
        for (int m = 0; m < 4; ++m)
            #pragma unroll
            for (int r = 0; r < 4; ++r){
                const int q = m*16 + quad*4 + r;
                const int key = w*64 + nt*16 + col;
                sE[q*264 + key] = f2bf(__expf(sacc[nt][m][r]));
            }
    __syncthreads();

    // ---- phase 2: wave w owns q-range [16w, 16w+16) ----
    const short* RT = (const short*)(wsb + RT_OFF) + b*80*256;
    float* HD = (float*)(wsb + HD_OFF) + (size_t)(b*NH + j)*NTQ*NF;
    const int q0 = w*16;
    f32x4 acc2[5];
    #pragma unroll
    for (int nt = 0; nt < 5; ++nt) acc2[nt] = (f32x4)0.f;
    #pragma unroll 2
    for (int kb = 0; kb < 8; ++kb){
        const int ko = kb*32 + quad*8;
        short8 a = *(const short8*)&sE[(q0 + col)*264 + ko];
        #pragma unroll
        for (int nt = 0; nt < 5; ++nt){
            short8 bb = ld8(RT + (nt*16 + col)*256 + ko);
            acc2[nt] = MFMA16(a, bb, acc2[nt]);
        }
    }
    __syncthreads();                       // all phase-2 sE reads done
    float* sH = (float*)sBuf;              // [64][40] heads staging
    #pragma unroll
    for (int nt = 0; nt < 5; ++nt)
        #pragma unroll
        for (int r = 0; r < 4; ++r){
            float v = acc2[nt][r];
            float o = __shfl_xor(v, 1, 64);
            if (!(col & 1)){
                const int f = nt*8 + (col >> 1);
                if (f < NF){
                    float num = v, den = o, h;
                    if (den != 0.0f) h = num/den;
                    else {
                        float s = 0.f;
                        for (int k = 0; k < NTK; ++k) s += value[(b*NTK + k)*NF + f];
                        h = s * (1.0f/256.0f);
                    }
                    sH[(q0 + quad*4 + r)*40 + f] = h;
                }
            }
        }
    __syncthreads();
    for (int idx = tid; idx < 64*NF; idx += 256){
        const int q = idx/NF, f = idx - q*NF;
        HD[(t0 + q)*NF + f] = sH[q*40 + f];
    }
}

// ---------------- kernel 3: fused head-mix MLP ----------------
__global__ void imta_final(const float* __restrict__ Wc, const float* __restrict__ bc,
                           const float* __restrict__ Wo1, const float* __restrict__ bo1,
                           const float* __restrict__ Wo2, const float* __restrict__ bo2,
                           const float* __restrict__ hd, float* __restrict__ out){
    const int bq = blockIdx.x;
    const int b = bq >> 8, qq = bq & 255;
    const int tid = threadIdx.x;
    __shared__ float sh[NF*NH];
    __shared__ float sW1[NF*NSF];
    for (int t = tid; t < NF*NH; t += 256){
        int jj = t/NF, f = t - jj*NF;
        sh[t] = hd[((b*NH + jj)*NTQ + qq)*NF + f];
    }
    if (tid < NF*NSF) sW1[tid] = Wo1[tid];
    __syncthreads();
    const int d = tid;
    float wcr[8];
    #pragma unroll
    for (int h = 0; h < 8; ++h) wcr[h] = Wc[h*ND + d];
    const float bcd = bc[d];
    float a2[6];
    #pragma unroll
    for (int s = 0; s < 6; ++s) a2[s] = bo1[s];
    #pragma unroll
    for (int f4 = 0; f4 < NF; f4 += 4){
        float4 sv[8];
        #pragma unroll
        for (int h = 0; h < 8; ++h) sv[h] = *(const float4*)&sh[h*NF + f4];
        #pragma unroll
        for (int fi = 0; fi < 4; ++fi){
            float a = bcd;
            #pragma unroll
            for (int h = 0; h < 8; ++h)
                a = fmaf(reinterpret_cast<const float*>(&sv[h])[fi], wcr[h], a);
            float lf = fast_tanh(a);
            const int f = f4 + fi;
            #pragma unroll
            for (int s = 0; s < 6; ++s)
                a2[s] = fmaf(lf, sW1[f*NSF + s], a2[s]);
        }
    }
    float o = bo2[d];
    #pragma unroll
    for (int s = 0; s < 6; ++s)
        o = fmaf(fast_tanh(a2[s]), Wo2[s], o);
    out[(b*NTQ + qq)*ND + d] = o;
}

extern "C" void kernel_launch(void* const* d_in, const int* in_sizes, int n_in,
                              void* d_out, int out_size, void* d_ws, size_t ws_size,
                              hipStream_t stream){
    const float* query  = (const float*)d_in[0];
    const float* key_ts = (const float*)d_in[1];
    const float* value  = (const float*)d_in[2];
    const float* mask   = (const float*)d_in[3];
    const float* Wq     = (const float*)d_in[4];
    const float* Wk     = (const float*)d_in[5];
    const float* Wc     = (const float*)d_in[6];
    const float* bc     = (const float*)d_in[7];
    const float* Wo1    = (const float*)d_in[8];
    const float* bo1    = (const float*)d_in[9];
    const float* Wo2    = (const float*)d_in[10];
    const float* bo2    = (const float*)d_in[11];
    char* wsb  = (char*)d_ws;
    float* out = (float*)d_out;
    (void)in_sizes; (void)n_in; (void)out_size; (void)ws_size;

    imta_pack <<<dim3(1792),     dim3(256), 0, stream>>>(query, key_ts, Wq, Wk, mask, value, wsb);
    imta_attn <<<dim3(4, 8, 16), dim3(256), 0, stream>>>(wsb, value);
    imta_final<<<dim3(4096),     dim3(256), 0, stream>>>(Wc, bc, Wo1, bo1, Wo2, bo2,
                                                         (const float*)(wsb + HD_OFF), out);
}

// Round 2
// 156.234 us; speedup vs baseline: 1.0620x; 1.0620x over previous
//
#include <hip/hip_runtime.h>

#define NB 16
#define NTQ 256
#define NTK 256
#define ND 256
#define NF 36
#define NH 8
#define NDK 32
#define NSF 6

typedef __attribute__((ext_vector_type(8))) short short8;
typedef __attribute__((ext_vector_type(4))) float f32x4;
#define MFMA16(a,b,c) __builtin_amdgcn_mfma_f32_16x16x32_bf16(a,b,c,0,0,0)

// ---- workspace byte offsets ----
// WqT/WkT hi/lo: [j*32+dk][d] bf16, 128KB each
#define WQTH_OFF 0u
#define WQTL_OFF (WQTH_OFF + 131072u)
#define WKTH_OFF (WQTH_OFF + 262144u)
#define WKTL_OFF (WQTH_OFF + 393216u)
// RT: [b][80][256] bf16 (f'=2f: m*v, f'=2f+1: m)
#define RT_OFF   (WQTH_OFF + 524288u)
// projected Q/K hi/lo: [b][j][t][dk] bf16, 4MB each
#define QPH_OFF  (2u*1024*1024)
#define QPL_OFF  (6u*1024*1024)
#define KPH_OFF  (10u*1024*1024)
#define KPL_OFF  (14u*1024*1024)
// HD: fp32 [b][j][t][f]
#define HD_OFF   (18u*1024*1024)
// total ~23 MB

__device__ __forceinline__ short f2bf(float x){
    union { float f; unsigned u; } v; v.f = x;
    unsigned r = v.u + 0x7fffu + ((v.u >> 16) & 1u);
    return (short)(r >> 16);
}
__device__ __forceinline__ float bf2f(short s){
    union { float f; unsigned u; } v; v.u = ((unsigned)(unsigned short)s) << 16;
    return v.f;
}
__device__ __forceinline__ float fast_tanh(float x){
    float e = __expf(2.0f*x);
    return 1.0f - 2.0f/(e + 1.0f);
}
__device__ __forceinline__ short8 ld8(const short* p){ return *(const short8*)p; }

// hi/lo bf16 split of 8 consecutive floats (RNE hi, RNE residual lo)
__device__ __forceinline__ void cvt8(const float* __restrict__ p, short8& h8, short8& l8){
    f32x4 a = *(const f32x4*)p;
    f32x4 c = *(const f32x4*)(p + 4);
    #pragma unroll
    for (int i = 0; i < 4; ++i){
        short h0 = f2bf(a[i]); h8[i]   = h0; l8[i]   = f2bf(a[i] - bf2f(h0));
        short h1 = f2bf(c[i]); h8[4+i] = h1; l8[4+i] = f2bf(c[i] - bf2f(h1));
    }
}

// ---------------- kernel 1: small pack (W transpose + RT) ----------------
// bid < 512: WqT/WkT transpose + hi/lo split; else RT pack
__global__ void imta_pack(const float* __restrict__ Wq, const float* __restrict__ Wk,
                          const float* __restrict__ mask, const float* __restrict__ value,
                          char* __restrict__ wsb){
    const int bid = blockIdx.x, tid = threadIdx.x;
    if (bid < 512){
        const int idx = bid*256 + tid;              // 131072 = 2 arrays * 65536
        const int arr = idx >> 16, rem = idx & 65535;
        const int d = rem & 255, jdk = rem >> 8;
        const int jj = jdk >> 5, dk = jdk & 31;
        const float* __restrict__ W = arr ? Wk : Wq;
        float v = W[(jj*ND + d)*NDK + dk];
        short h = f2bf(v);
        short* oh = (short*)(wsb + (arr ? WKTH_OFF : WQTH_OFF));
        short* ol = (short*)(wsb + (arr ? WKTL_OFF : WQTL_OFF));
        oh[rem] = h; ol[rem] = f2bf(v - bf2f(h));
        return;
    }
    const int rb = bid - 512;
    const int x = rb & 15, b = rb >> 4;
    const int k = tid;
    short* rt = (short*)(wsb + RT_OFF) + b*80*256;
    #pragma unroll
    for (int r = 0; r < 5; ++r){
        const int fp = x*5 + r;
        const int f = fp >> 1;
        short o = 0;
        if (f < NF){
            float m = mask[(b*NTK + k)*NF + f];
            o = (fp & 1) ? f2bf(m) : f2bf(m * value[(b*NTK + k)*NF + f]);
        }
        rt[fp*256 + k] = o;
    }
}

// ---------------- kernel 2: projection GEMM (no LDS, no barriers) ----------------
// grid (32, 2, 16): x -> {mtile = x>>1 (16 rows), colhalf = x&1 (128 cols)},
// y = side (0=Q,1=K), z = b. Wave w covers cols [c0 + 32w, c0 + 32w + 32).
// Inline fp32 -> bf16 hi/lo of X; W from packed bf16. Same MFMA order as before.
__global__ void imta_proj(const float* __restrict__ query, const float* __restrict__ key_ts,
                          char* __restrict__ wsb){
    const int t0 = (blockIdx.x >> 1)*16, c0 = (blockIdx.x & 1)*128;
    const int side = blockIdx.y, b = blockIdx.z;
    const int tid = threadIdx.x, w = tid >> 6, lane = tid & 63;
    const int col = lane & 15, quad = lane >> 4;

    const float* __restrict__ X = side ? key_ts : query;
    const short* WH = (const short*)(wsb + (side ? WKTH_OFF : WQTH_OFF));
    const short* WL = (const short*)(wsb + (side ? WKTL_OFF : WQTL_OFF));
    short* OH = (short*)(wsb + (side ? KPH_OFF : QPH_OFF));
    short* OL = (short*)(wsb + (side ? KPL_OFF : QPL_OFF));

    const int nbase = c0 + w*32;
    const float* xrow = X + (size_t)(b*NTQ + t0 + col)*ND;

    f32x4 acc[2]; acc[0] = (f32x4)0.f; acc[1] = (f32x4)0.f;
    #pragma unroll
    for (int kb = 0; kb < 8; ++kb){
        const int dko = kb*32 + quad*8;
        short8 ah, al;
        cvt8(xrow + dko, ah, al);
        #pragma unroll
        for (int nt = 0; nt < 2; ++nt){
            const int n = nbase + nt*16 + col;
            short8 bh = ld8(WH + n*ND + dko);
            short8 bl = ld8(WL + n*ND + dko);
            acc[nt] = MFMA16(al, bh, acc[nt]);
            acc[nt] = MFMA16(ah, bl, acc[nt]);
            acc[nt] = MFMA16(ah, bh, acc[nt]);
        }
    }
    #pragma unroll
    for (int nt = 0; nt < 2; ++nt){
        const int n = nbase + nt*16 + col;
        const int j = n >> 5, dk = n & 31;
        #pragma unroll
        for (int r = 0; r < 4; ++r){
            const int t = t0 + quad*4 + r;
            float v = acc[nt][r];
            short h = f2bf(v);
            size_t o = (size_t)(((b*NH + j)*NTQ + t)*NDK + dk);
            OH[o] = h; OL[o] = f2bf(v - bf2f(h));
        }
    }
}

// ---------------- kernel 3: attention via MFMA (round-0 verbatim) ----------------
// block: (qtile | j | b). phase1: scores (hi/lo 3-pass) -> exp -> E(bf16) in LDS
// phase2: E @ RT^T (interleaved mv/m cols) -> shfl div -> heads
__global__ void imta_attn(char* __restrict__ wsb, const float* __restrict__ value){
    const int t0 = blockIdx.x*64;
    const int j = blockIdx.y, b = blockIdx.z;
    const int tid = threadIdx.x, w = tid >> 6, lane = tid & 63;
    const int col = lane & 15, quad = lane >> 4;
    __shared__ short sE[64*264];               // 33.8 KB; later overlaid by sH
    const short* QH = (const short*)(wsb + QPH_OFF) + (b*NH + j)*NTQ*NDK;
    const short* QL = (const short*)(wsb + QPL_OFF) + (b*NH + j)*NTQ*NDK;
    const short* KH = (const short*)(wsb + KPH_OFF) + (b*NH + j)*NTK*NDK;
    const short* KL = (const short*)(wsb + KPL_OFF) + (b*NH + j)*NTK*NDK;
    const short* RT = (const short*)(wsb + RT_OFF) + b*80*256;
    float* HD = (float*)(wsb + HD_OFF) + (b*NH + j)*NTQ*NF;

    // phase 1: wave w covers keys [64w, 64w+64)
    short8 ah[4], al[4];
    #pragma unroll
    for (int m = 0; m < 4; ++m){
        const int t = t0 + m*16 + col;
        ah[m] = ld8(QH + t*NDK + quad*8);
        al[m] = ld8(QL + t*NDK + quad*8);
    }
    #pragma unroll
    for (int nt = 0; nt < 4; ++nt){
        const int key0 = w*64 + nt*16;
        short8 bh = ld8(KH + (key0 + col)*NDK + quad*8);
        short8 bl = ld8(KL + (key0 + col)*NDK + quad*8);
        f32x4 acc[4];
        #pragma unroll
        for (int m = 0; m < 4; ++m){
            f32x4 c = (f32x4)0.f;
            c = MFMA16(al[m], bh, c);
            c = MFMA16(ah[m], bl, c);
            c = MFMA16(ah[m], bh, c);
            acc[m] = c;
        }
        const int key = key0 + col;
        #pragma unroll
        for (int m = 0; m < 4; ++m)
            #pragma unroll
            for (int r = 0; r < 4; ++r){
                const int q = m*16 + quad*4 + r;
                sE[q*264 + key] = f2bf(__expf(acc[m][r]));
            }
    }
    __syncthreads();

    // phase 2: wave w owns q-range [16w, 16w+16)
    const int q0 = w*16;
    f32x4 acc2[5];
    #pragma unroll
    for (int nt = 0; nt < 5; ++nt) acc2[nt] = (f32x4)0.f;
    #pragma unroll 2
    for (int kb = 0; kb < 8; ++kb){
        const int ko = kb*32 + quad*8;
        short8 a = *(const short8*)&sE[(q0 + col)*264 + ko];
        #pragma unroll
        for (int nt = 0; nt < 5; ++nt){
            short8 bb = ld8(RT + (nt*16 + col)*256 + ko);
            acc2[nt] = MFMA16(a, bb, acc2[nt]);
        }
    }
    __syncthreads();                           // all phase-2 sE reads done
    float* sH = (float*)sE;                    // [64][40] heads staging
    #pragma unroll
    for (int nt = 0; nt < 5; ++nt)
        #pragma unroll
        for (int r = 0; r < 4; ++r){
            float v = acc2[nt][r];
            float o = __shfl_xor(v, 1, 64);
            if (!(col & 1)){
                const int f = nt*8 + (col >> 1);
                if (f < NF){
                    float num = v, den = o, h;
                    if (den != 0.0f) h = num/den;
                    else {
                        float s = 0.f;
                        for (int k = 0; k < NTK; ++k) s += value[(b*NTK + k)*NF + f];
                        h = s * (1.0f/256.0f);
                    }
                    sH[(q0 + quad*4 + r)*40 + f] = h;
                }
            }
        }
    __syncthreads();
    for (int idx = tid; idx < 64*NF; idx += 256){
        const int q = idx/NF, f = idx - q*NF;
        HD[(t0 + q)*NF + f] = sH[q*40 + f];
    }
}

// ---------------- kernel 4: fused head-mix MLP ----------------
__global__ void imta_final(const float* __restrict__ Wc, const float* __restrict__ bc,
                           const float* __restrict__ Wo1, const float* __restrict__ bo1,
                           const float* __restrict__ Wo2, const float* __restrict__ bo2,
                           const float* __restrict__ hd, float* __restrict__ out){
    const int bq = blockIdx.x;
    const int b = bq >> 8, qq = bq & 255;
    const int tid = threadIdx.x;
    __shared__ float sh[NF*NH];
    __shared__ float sW1[NF*NSF];
    for (int t = tid; t < NF*NH; t += 256){
        int jj = t/NF, f = t - jj*NF;
        sh[t] = hd[((b*NH + jj)*NTQ + qq)*NF + f];
    }
    if (tid < NF*NSF) sW1[tid] = Wo1[tid];
    __syncthreads();
    const int d = tid;
    float wcr[8];
    #pragma unroll
    for (int h = 0; h < 8; ++h) wcr[h] = Wc[h*ND + d];
    const float bcd = bc[d];
    float a2[6];
    #pragma unroll
    for (int s = 0; s < 6; ++s) a2[s] = bo1[s];
    #pragma unroll
    for (int f4 = 0; f4 < NF; f4 += 4){
        float4 sv[8];
        #pragma unroll
        for (int h = 0; h < 8; ++h) sv[h] = *(const float4*)&sh[h*NF + f4];
        #pragma unroll
        for (int fi = 0; fi < 4; ++fi){
            float a = bcd;
            #pragma unroll
            for (int h = 0; h < 8; ++h)
                a = fmaf(reinterpret_cast<const float*>(&sv[h])[fi], wcr[h], a);
            float lf = fast_tanh(a);
            const int f = f4 + fi;
            #pragma unroll
            for (int s = 0; s < 6; ++s)
                a2[s] = fmaf(lf, sW1[f*NSF + s], a2[s]);
        }
    }
    float o = bo2[d];
    #pragma unroll
    for (int s = 0; s < 6; ++s)
        o = fmaf(fast_tanh(a2[s]), Wo2[s], o);
    out[(b*NTQ + qq)*ND + d] = o;
}

extern "C" void kernel_launch(void* const* d_in, const int* in_sizes, int n_in,
                              void* d_out, int out_size, void* d_ws, size_t ws_size,
                              hipStream_t stream){
    const float* query  = (const float*)d_in[0];
    const float* key_ts = (const float*)d_in[1];
    const float* value  = (const float*)d_in[2];
    const float* mask   = (const float*)d_in[3];
    const float* Wq     = (const float*)d_in[4];
    const float* Wk     = (const float*)d_in[5];
    const float* Wc     = (const float*)d_in[6];
    const float* bc     = (const float*)d_in[7];
    const float* Wo1    = (const float*)d_in[8];
    const float* bo1    = (const float*)d_in[9];
    const float* Wo2    = (const float*)d_in[10];
    const float* bo2    = (const float*)d_in[11];
    char* wsb  = (char*)d_ws;
    float* out = (float*)d_out;
    (void)in_sizes; (void)n_in; (void)out_size; (void)ws_size;

    imta_pack <<<dim3(768),      dim3(256), 0, stream>>>(Wq, Wk, mask, value, wsb);
    imta_proj <<<dim3(32, 2, 16),dim3(256), 0, stream>>>(query, key_ts, wsb);
    imta_attn <<<dim3(4, 8, 16), dim3(256), 0, stream>>>(wsb, value);
    imta_final<<<dim3(4096),     dim3(256), 0, stream>>>(Wc, bc, Wo1, bo1, Wo2, bo2,
                                                         (const float*)(wsb + HD_OFF), out);
}